// Round 1
// baseline (705.605 us; speedup 1.0000x reference)
//
#include <hip/hip_runtime.h>

#define NN 100000
#define NE 1200000
#define FD 64
#define NPOS 100000
#define NNEG 100000

// ---------------- degree / norm ----------------

__global__ __launch_bounds__(256) void init_deg_kernel(float* __restrict__ deg, int n) {
    int i = blockIdx.x * 256 + threadIdx.x;
    if (i < n) deg[i] = 1.0f;  // self loop
}

__global__ __launch_bounds__(256) void deg_count_kernel(const int* __restrict__ dst,
                                                        float* __restrict__ deg, int e) {
    int i = blockIdx.x * 256 + threadIdx.x;
    if (i < e) atomicAdd(&deg[dst[i]], 1.0f);
}

__global__ __launch_bounds__(256) void dis_kernel(float* __restrict__ deg, int n) {
    int i = blockIdx.x * 256 + threadIdx.x;
    if (i < n) deg[i] = rsqrtf(deg[i]);  // deg >= 1 always
}

// ---------------- dense transform: H = (relu?)(X) @ W ----------------
// W: [64,64] row-major. Lane j holds column j of W in 64 VGPRs.
// Block = 256 threads = 4 waves; block processes 64 rows staged in LDS.

template <bool RELU>
__global__ __launch_bounds__(256) void gemm64_kernel(const float* __restrict__ X,
                                                     const float* __restrict__ W,
                                                     float* __restrict__ Hout, int n) {
    __shared__ float xs[64][64];
    const int lane = threadIdx.x & 63;
    const int wid = threadIdx.x >> 6;

    float w[64];
#pragma unroll
    for (int k = 0; k < 64; ++k) w[k] = W[k * 64 + lane];

    const int row0 = blockIdx.x * 64;

    // stage 64 rows of X (coalesced), optional relu
#pragma unroll
    for (int i = 0; i < 16; ++i) {
        int idx = threadIdx.x + i * 256;
        int r = idx >> 6, c = idx & 63;
        int row = row0 + r;
        float v = 0.0f;
        if (row < n) v = X[(size_t)row * 64 + c];
        if (RELU) v = fmaxf(v, 0.0f);
        xs[r][c] = v;
    }
    __syncthreads();

    // each wave computes 16 rows; lane j computes output feature j
#pragma unroll 1
    for (int rr = 0; rr < 16; ++rr) {
        int r = wid * 16 + rr;
        int row = row0 + r;
        if (row < n) {
            float acc = 0.0f;
#pragma unroll
            for (int k = 0; k < 64; ++k) acc += xs[r][k] * w[k];
            Hout[(size_t)row * 64 + lane] = acc;
        }
    }
}

// ---------------- self-loop + bias init: Z = b + H * dis^2 ----------------
// one thread per float4 chunk (N*16 chunks)

__global__ __launch_bounds__(256) void selfloop_init_kernel(const float* __restrict__ H,
                                                            const float* __restrict__ dis,
                                                            const float* __restrict__ b,
                                                            float* __restrict__ Z, int n) {
    int i = blockIdx.x * 256 + threadIdx.x;
    if (i < n * 16) {
        int v = i >> 4;
        int c = i & 15;
        float d = dis[v];
        float d2 = d * d;
        float4 h4 = reinterpret_cast<const float4*>(H)[i];
        float4 b4 = reinterpret_cast<const float4*>(b)[c];
        float4 z4;
        z4.x = b4.x + h4.x * d2;
        z4.y = b4.y + h4.y * d2;
        z4.z = b4.z + h4.z * d2;
        z4.w = b4.w + h4.w * d2;
        reinterpret_cast<float4*>(Z)[i] = z4;
    }
}

// ---------------- edge aggregation: Z[dst] += H[src] * (dis[src]*dis[dst]) ----------------
// one 64-lane wave per edge

__global__ __launch_bounds__(256) void edge_agg_kernel(const int* __restrict__ src,
                                                       const int* __restrict__ dst,
                                                       const float* __restrict__ dis,
                                                       const float* __restrict__ H,
                                                       float* __restrict__ Z, int e) {
    const int lane = threadIdx.x & 63;
    const int edge = blockIdx.x * 4 + (threadIdx.x >> 6);
    if (edge < e) {
        int s = src[edge];
        int d = dst[edge];
        float nm = dis[s] * dis[d];
        float v = H[(size_t)s * 64 + lane] * nm;
        atomicAdd(&Z[(size_t)d * 64 + lane], v);
    }
}

// ---------------- decoder: logits[i] = dot(Z[a], Z[b]) ----------------
// one 64-lane wave per pair

__global__ __launch_bounds__(256) void decode_kernel(const int* __restrict__ pos,
                                                     const int* __restrict__ neg,
                                                     const float* __restrict__ Z,
                                                     float* __restrict__ out) {
    const int lane = threadIdx.x & 63;
    const int pair = blockIdx.x * 4 + (threadIdx.x >> 6);
    if (pair >= NPOS + NNEG) return;
    int a, b;
    if (pair < NPOS) {
        a = pos[pair];
        b = pos[NPOS + pair];
    } else {
        int p = pair - NPOS;
        a = neg[p];
        b = neg[NNEG + p];
    }
    float v = Z[(size_t)a * 64 + lane] * Z[(size_t)b * 64 + lane];
#pragma unroll
    for (int off = 32; off > 0; off >>= 1) v += __shfl_down(v, off, 64);
    if (lane == 0) out[pair] = v;
}

// ---------------- launch ----------------

extern "C" void kernel_launch(void* const* d_in, const int* in_sizes, int n_in,
                              void* d_out, int out_size, void* d_ws, size_t ws_size,
                              hipStream_t stream) {
    const float* x   = (const float*)d_in[0];
    const int*   ei  = (const int*)d_in[1];   // [2, NE]: src then dst
    const int*   pos = (const int*)d_in[2];   // [2, NPOS]
    const int*   neg = (const int*)d_in[3];   // [2, NNEG]
    const float* W1  = (const float*)d_in[4];
    const float* b1  = (const float*)d_in[5];
    const float* W2  = (const float*)d_in[6];
    const float* b2  = (const float*)d_in[7];
    float* out = (float*)d_out;

    char* ws = (char*)d_ws;
    float* dis  = (float*)ws;  // N floats (deg, then rsqrt in place)
    size_t off = ((size_t)NN * 4 + 255) / 256 * 256;
    float* bufA = (float*)(ws + off);                 // N*64
    float* bufB = bufA + (size_t)NN * 64;             // N*64

    const int* src = ei;
    const int* dst = ei + NE;

    // 1) degrees -> dis
    init_deg_kernel<<<(NN + 255) / 256, 256, 0, stream>>>(dis, NN);
    deg_count_kernel<<<(NE + 255) / 256, 256, 0, stream>>>(dst, dis, NE);
    dis_kernel<<<(NN + 255) / 256, 256, 0, stream>>>(dis, NN);

    // 2) layer 1: h1 = x @ W1 -> bufA
    gemm64_kernel<false><<<(NN + 63) / 64, 256, 0, stream>>>(x, W1, bufA, NN);
    //    z1 = b1 + h1*dis^2 (self loop) -> bufB, then += edges
    selfloop_init_kernel<<<(NN * 16 + 255) / 256, 256, 0, stream>>>(bufA, dis, b1, bufB, NN);
    edge_agg_kernel<<<(NE + 3) / 4, 256, 0, stream>>>(src, dst, dis, bufA, bufB, NE);

    // 3) layer 2: h2 = relu(z1) @ W2 -> bufA
    gemm64_kernel<true><<<(NN + 63) / 64, 256, 0, stream>>>(bufB, W2, bufA, NN);
    //    z2 = b2 + h2*dis^2 -> bufB, then += edges
    selfloop_init_kernel<<<(NN * 16 + 255) / 256, 256, 0, stream>>>(bufA, dis, b2, bufB, NN);
    edge_agg_kernel<<<(NE + 3) / 4, 256, 0, stream>>>(src, dst, dis, bufA, bufB, NE);

    // 4) decode
    decode_kernel<<<((NPOS + NNEG) + 3) / 4, 256, 0, stream>>>(pos, neg, bufB, out);
}

// Round 2
// 352.456 us; speedup vs baseline: 2.0020x; 2.0020x over previous
//
#include <hip/hip_runtime.h>

#define NN 100000
#define NE 1200000
#define NPOS 100000
#define NNEG 100000
#define NB_CNT ((NN + 255) / 256)   // 391 blocks for per-block scan

// ---------------- CSR build ----------------

__global__ __launch_bounds__(256) void zero_cnt_kernel(int* __restrict__ cnt, int n) {
    int i = blockIdx.x * 256 + threadIdx.x;
    if (i < n) cnt[i] = 0;
}

__global__ __launch_bounds__(256) void count_kernel(const int* __restrict__ dst,
                                                    int* __restrict__ cnt, int e) {
    int i = blockIdx.x * 256 + threadIdx.x;
    if (i < e) atomicAdd(&cnt[dst[i]], 1);
}

// per-block sums of cnt
__global__ __launch_bounds__(256) void scan1_kernel(const int* __restrict__ cnt,
                                                    int* __restrict__ bsum, int n) {
    __shared__ int tmp[256];
    int t = threadIdx.x;
    int i = blockIdx.x * 256 + t;
    int v = (i < n) ? cnt[i] : 0;
    tmp[t] = v;
    __syncthreads();
    for (int off = 128; off > 0; off >>= 1) {
        if (t < off) tmp[t] += tmp[t + off];
        __syncthreads();
    }
    if (t == 0) bsum[blockIdx.x] = tmp[0];
}

// exclusive scan of block sums (NB_CNT <= 512), also writes offs[n] = total
__global__ __launch_bounds__(512) void scan2_kernel(const int* __restrict__ bsum,
                                                    int* __restrict__ bsumex,
                                                    int* __restrict__ offs, int nb, int n) {
    __shared__ int tmp[512];
    int t = threadIdx.x;
    int v = (t < nb) ? bsum[t] : 0;
    tmp[t] = v;
    __syncthreads();
    for (int off = 1; off < 512; off <<= 1) {
        int add = (t >= off) ? tmp[t - off] : 0;
        __syncthreads();
        tmp[t] += add;
        __syncthreads();
    }
    if (t < nb) bsumex[t] = tmp[t] - v;   // exclusive
    if (t == nb - 1) offs[n] = tmp[t];    // total
}

// per-element exclusive scan within block + base; writes offs, cursor, dis
__global__ __launch_bounds__(256) void scan3_kernel(const int* __restrict__ cnt,
                                                    const int* __restrict__ bsumex,
                                                    int* __restrict__ offs,
                                                    int* __restrict__ cursor,
                                                    float* __restrict__ dis, int n) {
    __shared__ int tmp[256];
    int t = threadIdx.x;
    int i = blockIdx.x * 256 + t;
    int c = (i < n) ? cnt[i] : 0;
    tmp[t] = c;
    __syncthreads();
    for (int off = 1; off < 256; off <<= 1) {
        int add = (t >= off) ? tmp[t - off] : 0;
        __syncthreads();
        tmp[t] += add;
        __syncthreads();
    }
    if (i < n) {
        int excl = tmp[t] - c + bsumex[blockIdx.x];
        offs[i] = excl;
        cursor[i] = excl;
        dis[i] = rsqrtf((float)(c + 1));  // deg = in-degree + self-loop >= 1
    }
}

__global__ __launch_bounds__(256) void fill_kernel(const int* __restrict__ src,
                                                   const int* __restrict__ dst,
                                                   int* __restrict__ cursor,
                                                   int* __restrict__ csr, int e) {
    int i = blockIdx.x * 256 + threadIdx.x;
    if (i < e) {
        int d = dst[i];
        int p = atomicAdd(&cursor[d], 1);
        csr[p] = src[i];
    }
}

// ---------------- dense transform: H' = (relu?)(X) @ W  [* dis[row]] ----------------

template <bool RELU, bool SCALE>
__global__ __launch_bounds__(256) void gemm64_kernel(const float* __restrict__ X,
                                                     const float* __restrict__ W,
                                                     const float* __restrict__ dis,
                                                     float* __restrict__ Hout, int n) {
    __shared__ float xs[64][64];
    const int lane = threadIdx.x & 63;
    const int wid = threadIdx.x >> 6;

    float w[64];
#pragma unroll
    for (int k = 0; k < 64; ++k) w[k] = W[k * 64 + lane];

    const int row0 = blockIdx.x * 64;

#pragma unroll
    for (int i = 0; i < 16; ++i) {
        int idx = threadIdx.x + i * 256;
        int r = idx >> 6, c = idx & 63;
        int row = row0 + r;
        float v = 0.0f;
        if (row < n) v = X[(size_t)row * 64 + c];
        if (RELU) v = fmaxf(v, 0.0f);
        xs[r][c] = v;
    }
    __syncthreads();

#pragma unroll 1
    for (int rr = 0; rr < 16; ++rr) {
        int r = wid * 16 + rr;
        int row = row0 + r;
        if (row < n) {
            float acc = 0.0f;
#pragma unroll
            for (int k = 0; k < 64; ++k) acc += xs[r][k] * w[k];
            if (SCALE) acc *= dis[row];
            Hout[(size_t)row * 64 + lane] = acc;
        }
    }
}

// ---------------- gather aggregation: Z[v] = dis[v]*(H'[v] + sum_in H'[s]) + b ----------------

__global__ __launch_bounds__(256) void agg_kernel(const int* __restrict__ csr,
                                                  const int* __restrict__ offs,
                                                  const float* __restrict__ dis,
                                                  const float* __restrict__ Hp,
                                                  const float* __restrict__ bias,
                                                  float* __restrict__ Z, int n) {
    const int lane = threadIdx.x & 63;
    int v = blockIdx.x * 4 + (threadIdx.x >> 6);
    if (v >= n) return;
    v = __builtin_amdgcn_readfirstlane(v);
    const int e0 = __builtin_amdgcn_readfirstlane(offs[v]);
    const int e1 = __builtin_amdgcn_readfirstlane(offs[v + 1]);
    float acc0 = Hp[(size_t)v * 64 + lane];  // self loop
    float acc1 = 0.0f;
    int e = e0;
    for (; e + 2 <= e1; e += 2) {
        int sa = csr[e];
        int sb = csr[e + 1];
        acc0 += Hp[(size_t)sa * 64 + lane];
        acc1 += Hp[(size_t)sb * 64 + lane];
    }
    if (e < e1) acc1 += Hp[(size_t)csr[e] * 64 + lane];
    Z[(size_t)v * 64 + lane] = (acc0 + acc1) * dis[v] + bias[lane];
}

// ---------------- decoder ----------------

__global__ __launch_bounds__(256) void decode_kernel(const int* __restrict__ pos,
                                                     const int* __restrict__ neg,
                                                     const float* __restrict__ Z,
                                                     float* __restrict__ out) {
    const int lane = threadIdx.x & 63;
    const int pair = blockIdx.x * 4 + (threadIdx.x >> 6);
    if (pair >= NPOS + NNEG) return;
    int a, b;
    if (pair < NPOS) {
        a = pos[pair];
        b = pos[NPOS + pair];
    } else {
        int p = pair - NPOS;
        a = neg[p];
        b = neg[NNEG + p];
    }
    float v = Z[(size_t)a * 64 + lane] * Z[(size_t)b * 64 + lane];
#pragma unroll
    for (int off = 32; off > 0; off >>= 1) v += __shfl_down(v, off, 64);
    if (lane == 0) out[pair] = v;
}

// ---------------- fallback (round-0 atomic path) ----------------

__global__ __launch_bounds__(256) void init_deg_kernel(float* __restrict__ deg, int n) {
    int i = blockIdx.x * 256 + threadIdx.x;
    if (i < n) deg[i] = 1.0f;
}
__global__ __launch_bounds__(256) void deg_count_kernel(const int* __restrict__ dst,
                                                        float* __restrict__ deg, int e) {
    int i = blockIdx.x * 256 + threadIdx.x;
    if (i < e) atomicAdd(&deg[dst[i]], 1.0f);
}
__global__ __launch_bounds__(256) void dis_kernel(float* __restrict__ deg, int n) {
    int i = blockIdx.x * 256 + threadIdx.x;
    if (i < n) deg[i] = rsqrtf(deg[i]);
}
__global__ __launch_bounds__(256) void selfloop_init_kernel(const float* __restrict__ H,
                                                            const float* __restrict__ dis,
                                                            const float* __restrict__ b,
                                                            float* __restrict__ Z, int n) {
    int i = blockIdx.x * 256 + threadIdx.x;
    if (i < n * 16) {
        int v = i >> 4, c = i & 15;
        float d = dis[v], d2 = d * d;
        float4 h4 = reinterpret_cast<const float4*>(H)[i];
        float4 b4 = reinterpret_cast<const float4*>(b)[c];
        float4 z4;
        z4.x = b4.x + h4.x * d2;
        z4.y = b4.y + h4.y * d2;
        z4.z = b4.z + h4.z * d2;
        z4.w = b4.w + h4.w * d2;
        reinterpret_cast<float4*>(Z)[i] = z4;
    }
}
__global__ __launch_bounds__(256) void edge_agg_kernel(const int* __restrict__ src,
                                                       const int* __restrict__ dst,
                                                       const float* __restrict__ dis,
                                                       const float* __restrict__ H,
                                                       float* __restrict__ Z, int e) {
    const int lane = threadIdx.x & 63;
    const int edge = blockIdx.x * 4 + (threadIdx.x >> 6);
    if (edge < e) {
        int s = src[edge];
        int d = dst[edge];
        float nm = dis[s] * dis[d];
        float v = H[(size_t)s * 64 + lane] * nm;
        atomicAdd(&Z[(size_t)d * 64 + lane], v);
    }
}

// ---------------- launch ----------------

extern "C" void kernel_launch(void* const* d_in, const int* in_sizes, int n_in,
                              void* d_out, int out_size, void* d_ws, size_t ws_size,
                              hipStream_t stream) {
    const float* x   = (const float*)d_in[0];
    const int*   ei  = (const int*)d_in[1];
    const int*   pos = (const int*)d_in[2];
    const int*   neg = (const int*)d_in[3];
    const float* W1  = (const float*)d_in[4];
    const float* b1  = (const float*)d_in[5];
    const float* W2  = (const float*)d_in[6];
    const float* b2  = (const float*)d_in[7];
    float* out = (float*)d_out;

    const int* src = ei;
    const int* dst = ei + NE;

    char* ws = (char*)d_ws;
    size_t o = 0;
    auto alloc = [&](size_t bytes) {
        size_t p = o;
        o = (o + bytes + 255) & ~(size_t)255;
        return p;
    };
    float* dis    = (float*)(ws + alloc((size_t)NN * 4));
    int*   cnt    = (int*)  (ws + alloc((size_t)NN * 4));
    int*   offs   = (int*)  (ws + alloc((size_t)(NN + 1) * 4));
    int*   cursor = (int*)  (ws + alloc((size_t)NN * 4));
    int*   bsum   = (int*)  (ws + alloc((size_t)NB_CNT * 4));
    int*   bsumex = (int*)  (ws + alloc((size_t)NB_CNT * 4));
    int*   csr    = (int*)  (ws + alloc((size_t)NE * 4));
    float* bufA   = (float*)(ws + alloc((size_t)NN * 64 * 4));
    float* bufB   = (float*)(ws + alloc((size_t)NN * 64 * 4));

    if (o <= ws_size) {
        // ---- CSR gather path ----
        zero_cnt_kernel<<<NB_CNT, 256, 0, stream>>>(cnt, NN);
        count_kernel<<<(NE + 255) / 256, 256, 0, stream>>>(dst, cnt, NE);
        scan1_kernel<<<NB_CNT, 256, 0, stream>>>(cnt, bsum, NN);
        scan2_kernel<<<1, 512, 0, stream>>>(bsum, bsumex, offs, NB_CNT, NN);
        scan3_kernel<<<NB_CNT, 256, 0, stream>>>(cnt, bsumex, offs, cursor, dis, NN);
        fill_kernel<<<(NE + 255) / 256, 256, 0, stream>>>(src, dst, cursor, csr, NE);

        gemm64_kernel<false, true><<<(NN + 63) / 64, 256, 0, stream>>>(x, W1, dis, bufA, NN);
        agg_kernel<<<(NN + 3) / 4, 256, 0, stream>>>(csr, offs, dis, bufA, b1, bufB, NN);

        gemm64_kernel<true, true><<<(NN + 63) / 64, 256, 0, stream>>>(bufB, W2, dis, bufA, NN);
        agg_kernel<<<(NN + 3) / 4, 256, 0, stream>>>(csr, offs, dis, bufA, b2, bufB, NN);

        decode_kernel<<<((NPOS + NNEG) + 3) / 4, 256, 0, stream>>>(pos, neg, bufB, out);
    } else {
        // ---- fallback: atomic scatter path (round 0) ----
        float* fdis  = (float*)ws;
        size_t foff = ((size_t)NN * 4 + 255) / 256 * 256;
        float* fA = (float*)(ws + foff);
        float* fB = fA + (size_t)NN * 64;

        init_deg_kernel<<<(NN + 255) / 256, 256, 0, stream>>>(fdis, NN);
        deg_count_kernel<<<(NE + 255) / 256, 256, 0, stream>>>(dst, fdis, NE);
        dis_kernel<<<(NN + 255) / 256, 256, 0, stream>>>(fdis, NN);

        gemm64_kernel<false, false><<<(NN + 63) / 64, 256, 0, stream>>>(x, W1, nullptr, fA, NN);
        selfloop_init_kernel<<<(NN * 16 + 255) / 256, 256, 0, stream>>>(fA, fdis, b1, fB, NN);
        edge_agg_kernel<<<(NE + 3) / 4, 256, 0, stream>>>(src, dst, fdis, fA, fB, NE);

        gemm64_kernel<true, false><<<(NN + 63) / 64, 256, 0, stream>>>(fB, W2, nullptr, fA, NN);
        selfloop_init_kernel<<<(NN * 16 + 255) / 256, 256, 0, stream>>>(fA, fdis, b2, fB, NN);
        edge_agg_kernel<<<(NE + 3) / 4, 256, 0, stream>>>(src, dst, fdis, fA, fB, NE);

        decode_kernel<<<((NPOS + NNEG) + 3) / 4, 256, 0, stream>>>(pos, neg, fB, out);
    }
}